// Round 10
// baseline (6008.121 us; speedup 1.0000x reference)
//
#include <hip/hip_runtime.h>

#define NB 64      // batch
#define NS 512     // seq len
#define NE 512     // emb dim
#define NH 512     // per-dir hidden
#define NG 2048    // 4*NH
#define NT 64      // tags
#define KC 1024    // combined K = NE + NH
#define HB 16777216   // u16 elements per direction in HALL
#define SENT32 0x7FC07FC0u  // bf16 NaN|NaN — unreachable for h = sig*tanh
#define NEGV (-10000.0f)

typedef __attribute__((ext_vector_type(8))) short bf16x8;
typedef __attribute__((ext_vector_type(4))) float f32x4;
typedef unsigned short u16;
typedef unsigned int u32;
typedef unsigned long long u64;

__device__ __forceinline__ u16 f2bf(float x) {
    unsigned u = __builtin_bit_cast(unsigned, x);
    u += 0x7fffu + ((u >> 16) & 1u);
    return (u16)(u >> 16);
}
__device__ __forceinline__ float bf2f(u16 x) {
    return __builtin_bit_cast(float, (u32)x << 16);
}
__device__ __forceinline__ float sig_(float x) {
    return __builtin_amdgcn_rcpf(1.0f + __builtin_amdgcn_exp2f(-1.44269504f * x));
}
__device__ __forceinline__ float tanh_(float x) {
    return 2.0f * __builtin_amdgcn_rcpf(1.0f + __builtin_amdgcn_exp2f(-2.88539009f * x)) - 1.0f;
}
__device__ __forceinline__ bool ok64(u64 v) {
    return ((u32)v != SENT32) & ((u32)(v >> 32) != SENT32);
}

// ---------- prep: combined [W_ih | W_hh] -> bf16, [2][2048][1024] ----------
__global__ void prep_wcomb(const float* __restrict__ wihf, const float* __restrict__ whhf,
                           const float* __restrict__ wihb, const float* __restrict__ whhb,
                           u16* __restrict__ wcomb) {
    int idx = blockIdx.x * 256 + threadIdx.x;   // 1,048,576 threads, 4 elems each
    int base = idx * 4;
    int d = base >> 21;
    int rem = base & ((1 << 21) - 1);
    int n = rem >> 10;
    int k = rem & 1023;
    const float* wih = d ? wihb : wihf;
    const float* whh = d ? whhb : whhf;
    const float* src = (k < NE) ? (wih + n * NE + k) : (whh + n * NH + (k - NE));
    float4 v = *reinterpret_cast<const float4*>(src);
    ushort4 o;
    o.x = f2bf(v.x); o.y = f2bf(v.y); o.z = f2bf(v.z); o.w = f2bf(v.w);
    *reinterpret_cast<ushort4*>(wcomb + base) = o;
}

// ---------- prep: w_out->bf16, bias = b_ih+b_hh ----------
__global__ void prep_misc(const float* __restrict__ wout,
                          const float* __restrict__ bihf, const float* __restrict__ bhhf,
                          const float* __restrict__ bihb, const float* __restrict__ bhhb,
                          u16* __restrict__ woutbf, float* __restrict__ bias) {
    int idx = blockIdx.x * 256 + threadIdx.x;   // 272 blocks = 69,632 threads
    if (idx < 65536) { woutbf[idx] = f2bf(wout[idx]); return; }
    idx -= 65536;
    if (idx < 4096) {
        int d = idx >> 11, g = idx & 2047;
        bias[idx] = d ? (bihb[g] + bhhb[g]) : (bihf[g] + bhhf[g]);
    }
}

// ---------- prep: sentinel-fill HALL (64 MiB) ----------
__global__ void prep_hfill(uint4* __restrict__ h) {
    int idx = blockIdx.x * 256 + threadIdx.x;   // 16384 blocks
    uint4 v = {SENT32, SENT32, SENT32, SENT32};
    h[idx] = v;
}

// ---------- prep: embedding gather -> x_bf[(s*64+b)][512] bf16 ----------
__global__ void prep_embed(const float* __restrict__ emb, const int* __restrict__ sents,
                           u16* __restrict__ xbf) {
    int idx = blockIdx.x * 256 + threadIdx.x;   // 4,194,304 threads, 4 elems each
    int m = idx >> 7;
    int e = (idx & 127) << 2;
    int s = m >> 6, b = m & 63;
    int tok = sents[b * NS + s];
    float4 v = *reinterpret_cast<const float4*>(emb + (size_t)tok * NE + e);
    ushort4 o;
    o.x = f2bf(v.x); o.y = f2bf(v.y); o.z = f2bf(v.z); o.w = f2bf(v.w);
    *reinterpret_cast<ushort4*>(xbf + (size_t)m * NE + e) = o;
}

// ---------- persistent bi-LSTM: grid (32 jblk, 2 dir), 512 thr, 8 waves ----------
// Iteration layout (ONE barrier per step, bf16 parity gred):
//  h-waves (w4-7): epilogue(s) from gredb[par] -> publish h[s] -> poll h[s]
//                  (all blocks publish concurrently; visibility RTs overlap)
//                  -> h-MFMA partials(s+1) -> dump gredb[par^1]
//  x-waves (w0-3): x-MFMA partials(s+1) from prefetched regs -> issue
//                  prefetch x(s+2) -> dump gredb[par^1]   (off critical path)
//  barrier.
__global__ __launch_bounds__(512, 1)
void lstm_persist(const u16* __restrict__ xbf, const u16* __restrict__ wcomb,
                  const float* __restrict__ bias, u16* __restrict__ hall) {
    const int jblk = blockIdx.x;   // 0..31 -> j slice of 16
    const int dir  = blockIdx.y;   // 0 fwd, 1 bwd
    const int t = threadIdx.x;
    const int w = t >> 6, l = t & 63;
    const int l16 = l & 15, lhi = l >> 4;
    const int kbase = w * 128;
    const bool isx = (w < 4);

    __shared__ u16 gredb[2][8][64][36];   // 147 KiB bf16 parity partial buffer

    // ---- B-fragments in registers (once): 4 gates x 4 k-tiles ----
    bf16x8 bfrag[4][4];
#pragma unroll
    for (int nf = 0; nf < 4; ++nf)
#pragma unroll
        for (int kt = 0; kt < 4; ++kt) {
            int gr = nf * NH + jblk * 16 + l16;          // gate nf, j-col l16
            int k = kbase + kt * 32 + lhi * 8;
            bfrag[nf][kt] = *reinterpret_cast<const bf16x8*>(
                wcomb + (size_t)(dir * NG + gr) * KC + k);
        }

    // ---- epilogue ownership (h-waves, t >= 256): bb = tt>>2, j0 = (tt&3)*4 ----
    const int tt = t & 255;
    const int bb = tt >> 2;
    const int jq = tt & 3;
    const int j0 = jq * 4;
    float breg[4][4];
    if (!isx) {
#pragma unroll
        for (int gi = 0; gi < 4; ++gi)
#pragma unroll
            for (int u = 0; u < 4; ++u)
                breg[gi][u] = bias[dir * NG + gi * NH + jblk * 16 + j0 + u];
    }
    float cc[4] = {0.f, 0.f, 0.f, 0.f};

    u64* HWq = reinterpret_cast<u64*>(hall) + (size_t)dir * (HB / 4);
    const u64* Hq = HWq;

    f32x4 acc[4][4];
    bf16x8 xpre[4][4];

    // ---- pre-loop: partials for first step into gredb[0] ----
    {
        const int s0 = dir ? (NS - 1) : 0;
#pragma unroll
        for (int mf = 0; mf < 4; ++mf)
#pragma unroll
            for (int nf = 0; nf < 4; ++nf)
                acc[mf][nf] = (f32x4){0.f, 0.f, 0.f, 0.f};
        if (isx) {
            const u16* Abase = xbf + (size_t)(s0 * NB) * NE + kbase;
#pragma unroll
            for (int kt = 0; kt < 4; ++kt) {
                int k = kt * 32 + lhi * 8;
#pragma unroll
                for (int mf = 0; mf < 4; ++mf) {
                    bf16x8 a = *reinterpret_cast<const bf16x8*>(Abase + (size_t)(mf * 16 + l16) * NE + k);
#pragma unroll
                    for (int nf = 0; nf < 4; ++nf)
                        acc[mf][nf] = __builtin_amdgcn_mfma_f32_16x16x32_bf16(a, bfrag[nf][kt], acc[mf][nf], 0, 0, 0);
                }
            }
            const int s1 = dir ? (NS - 2) : 1;
            const u16* Pbase = xbf + (size_t)(s1 * NB) * NE + kbase;
#pragma unroll
            for (int kt = 0; kt < 4; ++kt)
#pragma unroll
                for (int mf = 0; mf < 4; ++mf)
                    xpre[kt][mf] = *reinterpret_cast<const bf16x8*>(
                        Pbase + (size_t)(mf * 16 + l16) * NE + kt * 32 + lhi * 8);
        }
#pragma unroll
        for (int mf = 0; mf < 4; ++mf)
#pragma unroll
            for (int nf = 0; nf < 4; ++nf)
#pragma unroll
                for (int r = 0; r < 4; ++r)
                    gredb[0][w][mf * 16 + lhi * 4 + r][nf * 16 + l16] = f2bf(acc[mf][nf][r]);
        __syncthreads();
    }

    for (int it = 0; it < NS; ++it) {
        const int s = dir ? (NS - 1 - it) : it;
        const int par = it & 1;
        const bool lastit = (it == NS - 1);

        if (!isx) {
            // ---- epilogue(s): bf16 gred reduce, cell update, publish ----
            float g[4][4];
#pragma unroll
            for (int gi = 0; gi < 4; ++gi) {
                f32x4 s4 = {0.f, 0.f, 0.f, 0.f};
#pragma unroll
                for (int w2 = 0; w2 < 8; ++w2) {
                    u64 v = *reinterpret_cast<const u64*>(&gredb[par][w2][bb][gi * 16 + j0]);
                    s4[0] += bf2f((u16)v);
                    s4[1] += bf2f((u16)(v >> 16));
                    s4[2] += bf2f((u16)(v >> 32));
                    s4[3] += bf2f((u16)(v >> 48));
                }
#pragma unroll
                for (int u = 0; u < 4; ++u) g[gi][u] = s4[u] + breg[gi][u];
            }
            u64 hw = 0;
#pragma unroll
            for (int u = 0; u < 4; ++u) {
                float cn = sig_(g[1][u]) * cc[u] + sig_(g[0][u]) * tanh_(g[2][u]);
                cc[u] = cn;
                hw |= (u64)f2bf(sig_(g[3][u]) * tanh_(cn)) << (u * 16);
            }
            __hip_atomic_store(HWq + (size_t)(s * NB + bb) * 128 + jblk * 4 + jq, hw,
                               __ATOMIC_RELAXED, __HIP_MEMORY_SCOPE_AGENT);

            if (!lastit) {
                // ---- poll h[s] (all blocks publishing concurrently) ----
                const int kloc = kbase - 512;
                u64 q[4][4][2];
                u32 okm = 0;   // bit = kt*8 + mf*2 + half
#pragma unroll
                for (int kt = 0; kt < 4; ++kt) {
                    int j = kloc + kt * 32 + lhi * 8;
#pragma unroll
                    for (int mf = 0; mf < 4; ++mf) {
                        const u64* P = Hq + (size_t)(s * NB + mf * 16 + l16) * 128 + (j >> 2);
                        u64 v0 = __hip_atomic_load(P,     __ATOMIC_RELAXED, __HIP_MEMORY_SCOPE_AGENT);
                        u64 v1 = __hip_atomic_load(P + 1, __ATOMIC_RELAXED, __HIP_MEMORY_SCOPE_AGENT);
                        q[kt][mf][0] = v0; q[kt][mf][1] = v1;
                        okm |= (ok64(v0) ? 1u : 0u) << (kt * 8 + mf * 2);
                        okm |= (ok64(v1) ? 1u : 0u) << (kt * 8 + mf * 2 + 1);
                    }
                }
                while (__ballot(okm != 0xFFFFFFFFu)) {
                    __builtin_amdgcn_s_sleep(1);
#pragma unroll
                    for (int kt = 0; kt < 4; ++kt) {
                        int j = kloc + kt * 32 + lhi * 8;
#pragma unroll
                        for (int mf = 0; mf < 4; ++mf) {
                            const u64* P = Hq + (size_t)(s * NB + mf * 16 + l16) * 128 + (j >> 2);
                            u32 b0 = 1u << (kt * 8 + mf * 2);
                            u32 b1 = b0 << 1;
                            if (!(okm & b0)) {
                                u64 v = __hip_atomic_load(P, __ATOMIC_RELAXED, __HIP_MEMORY_SCOPE_AGENT);
                                q[kt][mf][0] = v;
                                if (ok64(v)) okm |= b0;
                            }
                            if (!(okm & b1)) {
                                u64 v = __hip_atomic_load(P + 1, __ATOMIC_RELAXED, __HIP_MEMORY_SCOPE_AGENT);
                                q[kt][mf][1] = v;
                                if (ok64(v)) okm |= b1;
                            }
                        }
                    }
                }
                __builtin_amdgcn_sched_barrier(0);
#pragma unroll
                for (int mf = 0; mf < 4; ++mf)
#pragma unroll
                    for (int nf = 0; nf < 4; ++nf)
                        acc[mf][nf] = (f32x4){0.f, 0.f, 0.f, 0.f};
#pragma unroll
                for (int kt = 0; kt < 4; ++kt) {
#pragma unroll
                    for (int mf = 0; mf < 4; ++mf) {
                        union { u64 qq[2]; bf16x8 v; } cv;
                        cv.qq[0] = q[kt][mf][0]; cv.qq[1] = q[kt][mf][1];
#pragma unroll
                        for (int nf = 0; nf < 4; ++nf)
                            acc[mf][nf] = __builtin_amdgcn_mfma_f32_16x16x32_bf16(cv.v, bfrag[nf][kt], acc[mf][nf], 0, 0, 0);
                    }
                }
#pragma unroll
                for (int mf = 0; mf < 4; ++mf)
#pragma unroll
                    for (int nf = 0; nf < 4; ++nf)
#pragma unroll
                        for (int r = 0; r < 4; ++r)
                            gredb[par ^ 1][w][mf * 16 + lhi * 4 + r][nf * 16 + l16] = f2bf(acc[mf][nf][r]);
            }
        } else if (!lastit) {
            // ---- x-waves: x-MFMA(s+1) from regs; prefetch x(s+2); dump ----
#pragma unroll
            for (int mf = 0; mf < 4; ++mf)
#pragma unroll
                for (int nf = 0; nf < 4; ++nf)
                    acc[mf][nf] = (f32x4){0.f, 0.f, 0.f, 0.f};
#pragma unroll
            for (int kt = 0; kt < 4; ++kt)
#pragma unroll
                for (int mf = 0; mf < 4; ++mf)
#pragma unroll
                    for (int nf = 0; nf < 4; ++nf)
                        acc[mf][nf] = __builtin_amdgcn_mfma_f32_16x16x32_bf16(xpre[kt][mf], bfrag[nf][kt], acc[mf][nf], 0, 0, 0);
            if (it + 2 < NS) {
                const int s2 = dir ? (s - 2) : (s + 2);
                const u16* Pbase = xbf + (size_t)(s2 * NB) * NE + kbase;
#pragma unroll
                for (int kt = 0; kt < 4; ++kt)
#pragma unroll
                    for (int mf = 0; mf < 4; ++mf)
                        xpre[kt][mf] = *reinterpret_cast<const bf16x8*>(
                            Pbase + (size_t)(mf * 16 + l16) * NE + kt * 32 + lhi * 8);
            }
#pragma unroll
            for (int mf = 0; mf < 4; ++mf)
#pragma unroll
                for (int nf = 0; nf < 4; ++nf)
#pragma unroll
                    for (int r = 0; r < 4; ++r)
                        gredb[par ^ 1][w][mf * 16 + lhi * 4 + r][nf * 16 + l16] = f2bf(acc[mf][nf][r]);
        }

        if (!lastit) __syncthreads();
    }
}

// ---------- emissions: one block per s; rows b=0..63 ----------
__global__ void emis_kernel(const u16* __restrict__ hall, const u16* __restrict__ woutbf,
                            const float* __restrict__ bout, float* __restrict__ emis) {
    const int blk = blockIdx.x;                   // = s, 512 blocks
    const int t = threadIdx.x;
    const int w = t >> 6, l = t & 63;
    const int l16 = l & 15, lhi = l >> 4;

    const u16* arow0 = hall + (size_t)(blk * 64 + w * 16 + l16) * NH;
    const u16* arow1 = arow0 + HB;
    const u16* br0 = woutbf + (size_t)(0 * 16 + l16) * KC;
    const u16* br1 = woutbf + (size_t)(1 * 16 + l16) * KC;
    const u16* br2 = woutbf + (size_t)(2 * 16 + l16) * KC;
    const u16* br3 = woutbf + (size_t)(3 * 16 + l16) * KC;

    f32x4 a0 = {0.f,0.f,0.f,0.f}, a1 = {0.f,0.f,0.f,0.f}, a2 = {0.f,0.f,0.f,0.f}, a3 = {0.f,0.f,0.f,0.f};
#pragma unroll
    for (int kt = 0; kt < 16; ++kt) {             // h_f part
        int k = kt * 32 + lhi * 8;
        bf16x8 a = *reinterpret_cast<const bf16x8*>(arow0 + k);
        a0 = __builtin_amdgcn_mfma_f32_16x16x32_bf16(a, *reinterpret_cast<const bf16x8*>(br0 + k), a0, 0, 0, 0);
        a1 = __builtin_amdgcn_mfma_f32_16x16x32_bf16(a, *reinterpret_cast<const bf16x8*>(br1 + k), a1, 0, 0, 0);
        a2 = __builtin_amdgcn_mfma_f32_16x16x32_bf16(a, *reinterpret_cast<const bf16x8*>(br2 + k), a2, 0, 0, 0);
        a3 = __builtin_amdgcn_mfma_f32_16x16x32_bf16(a, *reinterpret_cast<const bf16x8*>(br3 + k), a3, 0, 0, 0);
    }
#pragma unroll
    for (int kt = 0; kt < 16; ++kt) {             // h_b part
        int k = kt * 32 + lhi * 8;
        bf16x8 a = *reinterpret_cast<const bf16x8*>(arow1 + k);
        a0 = __builtin_amdgcn_mfma_f32_16x16x32_bf16(a, *reinterpret_cast<const bf16x8*>(br0 + NH + k), a0, 0, 0, 0);
        a1 = __builtin_amdgcn_mfma_f32_16x16x32_bf16(a, *reinterpret_cast<const bf16x8*>(br1 + NH + k), a1, 0, 0, 0);
        a2 = __builtin_amdgcn_mfma_f32_16x16x32_bf16(a, *reinterpret_cast<const bf16x8*>(br2 + NH + k), a2, 0, 0, 0);
        a3 = __builtin_amdgcn_mfma_f32_16x16x32_bf16(a, *reinterpret_cast<const bf16x8*>(br3 + NH + k), a3, 0, 0, 0);
    }
#pragma unroll
    for (int r = 0; r < 4; ++r) {
        int gm = blk * 64 + w * 16 + lhi * 4 + r;
        emis[(size_t)gm * NT + 0 * 16 + l16] = a0[r] + bout[0 * 16 + l16];
        emis[(size_t)gm * NT + 1 * 16 + l16] = a1[r] + bout[1 * 16 + l16];
        emis[(size_t)gm * NT + 2 * 16 + l16] = a2[r] + bout[2 * 16 + l16];
        emis[(size_t)gm * NT + 3 * 16 + l16] = a3[r] + bout[3 * 16 + l16];
    }
}

// ---------- gold score per batch ----------
__global__ void gold_kernel(const float* __restrict__ emis, const int* __restrict__ tags,
                            const float* __restrict__ trans, float* __restrict__ gold) {
    int b = blockIdx.x, t = threadIdx.x;
    float acc = 0.f;
    for (int s = t; s < NS; s += 256) {
        int tag = tags[b * NS + s];
        int prev = (s == 0) ? 0 : tags[b * NS + s - 1];
        acc += emis[(size_t)(s * NB + b) * NT + tag] + trans[tag * NT + prev];
    }
    acc += __shfl_xor(acc, 1);  acc += __shfl_xor(acc, 2);  acc += __shfl_xor(acc, 4);
    acc += __shfl_xor(acc, 8);  acc += __shfl_xor(acc, 16); acc += __shfl_xor(acc, 32);
    __shared__ float red[4];
    if ((t & 63) == 0) red[t >> 6] = acc;
    __syncthreads();
    if (t == 0) gold[b] = red[0] + red[1] + red[2] + red[3];
}

// ---------- CRF forward: 1 wave/block, transitions column in regs, no LDS ----------
__global__ void crf_kernel(const float* __restrict__ emis, const float* __restrict__ trans,
                           float* __restrict__ fwd) {
    int b = blockIdx.x, l = threadIdx.x;   // 64 threads; lane l = "next" tag
    float Tc[64];
#pragma unroll
    for (int p = 0; p < 64; ++p)
        Tc[p] = trans[l * NT + p];         // T[prev=p][next=l]
    float a = (l == 0) ? 0.f : NEGV;       // alpha in a register per lane

    for (int s = 0; s < NS; ++s) {
        float emit = emis[(size_t)(s * NB + b) * NT + l];
        float M = -3.0e38f;
#pragma unroll
        for (int p = 0; p < 64; ++p)
            M = fmaxf(M, __shfl(a, p) + Tc[p]);
        float S = 0.f;
#pragma unroll
        for (int p = 0; p < 64; ++p)
            S += __builtin_amdgcn_exp2f((__shfl(a, p) + Tc[p] - M) * 1.44269504f);
        a = M + __builtin_amdgcn_logf(S) * 0.69314718f + emit;
    }
    // final logsumexp over the 64 lanes
    float M = a;
#pragma unroll
    for (int d = 1; d < 64; d <<= 1) M = fmaxf(M, __shfl_xor(M, d));
    float e = __builtin_amdgcn_exp2f((a - M) * 1.44269504f);
#pragma unroll
    for (int d = 1; d < 64; d <<= 1) e += __shfl_xor(e, d);
    if (l == 0) fwd[b] = M + __builtin_amdgcn_logf(e) * 0.69314718f;
}

// ---------- final: mean(fwd - gold) ----------
__global__ void final_kernel(const float* __restrict__ fwd, const float* __restrict__ gold,
                             float* __restrict__ out) {
    int t = threadIdx.x;   // 64
    float v = fwd[t] - gold[t];
    for (int d = 1; d < 64; d <<= 1) v += __shfl_xor(v, d);
    if (t == 0) out[0] = v * (1.0f / 64.0f);
}

extern "C" void kernel_launch(void* const* d_in, const int* in_sizes, int n_in,
                              void* d_out, int out_size, void* d_ws, size_t ws_size,
                              hipStream_t stream) {
    (void)in_sizes; (void)n_in; (void)out_size; (void)ws_size;
    const int* sents = (const int*)d_in[0];
    const int* tags  = (const int*)d_in[1];
    const float* emb  = (const float*)d_in[3];
    const float* wihf = (const float*)d_in[4];
    const float* whhf = (const float*)d_in[5];
    const float* bihf = (const float*)d_in[6];
    const float* bhhf = (const float*)d_in[7];
    const float* wihb = (const float*)d_in[8];
    const float* whhb = (const float*)d_in[9];
    const float* bihb = (const float*)d_in[10];
    const float* bhhb = (const float*)d_in[11];
    const float* wout = (const float*)d_in[12];
    const float* bout = (const float*)d_in[13];
    const float* trans = (const float*)d_in[14];

    char* ws = (char*)d_ws;
    u16*   WCOMB  = (u16*)(ws + 0);              //  8 MiB  [2][2048][1024] bf16
    u16*   WOUTBF = (u16*)(ws + 8388608);        //  128 KiB [64][1024] bf16
    float* BIAS   = (float*)(ws + 8519680);      //  16 KiB  [2][2048] f32
    u16*   XBF    = (u16*)(ws + 8536064);        //  32 MiB  [32768][512] bf16
    u16*   HALL   = (u16*)(ws + 42090496);       //  64 MiB  [2][512][64][512] bf16
    float* EMIS   = (float*)(ws + 109199360);    //  8 MiB   [512*64][64] f32
    float* FWD    = (float*)(ws + 117587968);    //  [64] f32
    float* GOLD   = (float*)(ws + 117588224);    //  [64] f32

    prep_wcomb<<<4096, 256, 0, stream>>>(wihf, whhf, wihb, whhb, WCOMB);
    prep_misc<<<272, 256, 0, stream>>>(wout, bihf, bhhf, bihb, bhhb, WOUTBF, BIAS);
    prep_hfill<<<16384, 256, 0, stream>>>((uint4*)HALL);
    prep_embed<<<16384, 256, 0, stream>>>(emb, sents, XBF);

    lstm_persist<<<dim3(32, 2), 512, 0, stream>>>(XBF, WCOMB, BIAS, HALL);

    emis_kernel<<<512, 256, 0, stream>>>(HALL, WOUTBF, bout, EMIS);
    gold_kernel<<<64, 256, 0, stream>>>(EMIS, tags, trans, GOLD);
    crf_kernel<<<64, 64, 0, stream>>>(EMIS, trans, FWD);
    final_kernel<<<1, 64, 0, stream>>>(FWD, GOLD, (float*)d_out);
}

// Round 11
// 4498.324 us; speedup vs baseline: 1.3356x; 1.3356x over previous
//
#include <hip/hip_runtime.h>

#define NB 64      // batch
#define NS 512     // seq len
#define NE 512     // emb dim
#define NH 512     // per-dir hidden
#define NG 2048    // 4*NH
#define NT 64      // tags
#define KC 1024    // combined K = NE + NH
#define HB 16777216   // u16 elements per direction in HALL
#define SENT32 0x7FC07FC0u  // bf16 NaN|NaN — unreachable for h = sig*tanh
#define NEGV (-10000.0f)

typedef __attribute__((ext_vector_type(8))) short bf16x8;
typedef __attribute__((ext_vector_type(4))) float f32x4;
typedef unsigned short u16;
typedef unsigned int u32;
typedef unsigned long long u64;

__device__ __forceinline__ u16 f2bf(float x) {
    unsigned u = __builtin_bit_cast(unsigned, x);
    u += 0x7fffu + ((u >> 16) & 1u);
    return (u16)(u >> 16);
}
__device__ __forceinline__ float sig_(float x) {
    return __builtin_amdgcn_rcpf(1.0f + __builtin_amdgcn_exp2f(-1.44269504f * x));
}
__device__ __forceinline__ float tanh_(float x) {
    return 2.0f * __builtin_amdgcn_rcpf(1.0f + __builtin_amdgcn_exp2f(-2.88539009f * x)) - 1.0f;
}

// ---------- prep: combined [W_ih | W_hh] -> bf16, [2][2048][1024] ----------
__global__ void prep_wcomb(const float* __restrict__ wihf, const float* __restrict__ whhf,
                           const float* __restrict__ wihb, const float* __restrict__ whhb,
                           u16* __restrict__ wcomb) {
    int idx = blockIdx.x * 256 + threadIdx.x;   // 1,048,576 threads, 4 elems each
    int base = idx * 4;
    int d = base >> 21;
    int rem = base & ((1 << 21) - 1);
    int n = rem >> 10;
    int k = rem & 1023;
    const float* wih = d ? wihb : wihf;
    const float* whh = d ? whhb : whhf;
    const float* src = (k < NE) ? (wih + n * NE + k) : (whh + n * NH + (k - NE));
    float4 v = *reinterpret_cast<const float4*>(src);
    ushort4 o;
    o.x = f2bf(v.x); o.y = f2bf(v.y); o.z = f2bf(v.z); o.w = f2bf(v.w);
    *reinterpret_cast<ushort4*>(wcomb + base) = o;
}

// ---------- prep: w_out->bf16, bias = b_ih+b_hh ----------
__global__ void prep_misc(const float* __restrict__ wout,
                          const float* __restrict__ bihf, const float* __restrict__ bhhf,
                          const float* __restrict__ bihb, const float* __restrict__ bhhb,
                          u16* __restrict__ woutbf, float* __restrict__ bias) {
    int idx = blockIdx.x * 256 + threadIdx.x;   // 272 blocks = 69,632 threads
    if (idx < 65536) { woutbf[idx] = f2bf(wout[idx]); return; }
    idx -= 65536;
    if (idx < 4096) {
        int d = idx >> 11, g = idx & 2047;
        bias[idx] = d ? (bihb[g] + bhhb[g]) : (bihf[g] + bhhf[g]);
    }
}

// ---------- prep: sentinel-fill HALL (64 MiB) ----------
__global__ void prep_hfill(uint4* __restrict__ h) {
    int idx = blockIdx.x * 256 + threadIdx.x;   // 16384 blocks
    uint4 v = {SENT32, SENT32, SENT32, SENT32};
    h[idx] = v;
}

// ---------- prep: embedding gather -> x_bf[(s*64+b)][512] bf16 ----------
__global__ void prep_embed(const float* __restrict__ emb, const int* __restrict__ sents,
                           u16* __restrict__ xbf) {
    int idx = blockIdx.x * 256 + threadIdx.x;   // 4,194,304 threads, 4 elems each
    int m = idx >> 7;
    int e = (idx & 127) << 2;
    int s = m >> 6, b = m & 63;
    int tok = sents[b * NS + s];
    float4 v = *reinterpret_cast<const float4*>(emb + (size_t)tok * NE + e);
    ushort4 o;
    o.x = f2bf(v.x); o.y = f2bf(v.y); o.z = f2bf(v.z); o.w = f2bf(v.w);
    *reinterpret_cast<ushort4*>(xbf + (size_t)m * NE + e) = o;
}

// ---------- persistent bi-LSTM: grid (32 jblk, 2 dir), 512 thr, 8 waves ----------
// r7 protocol (best measured: 7.35 us/step): sentinel-in-data, narrow
// per-fragment retry, poll at iteration top (full epilogue+dump+barrier of
// slack after publish), fire-and-forget relaxed agent publish.
// Only change vs r7: gred padded 68->69 (epilogue reads 4-way -> 2-way).
__global__ __launch_bounds__(512, 1)
void lstm_persist(const u16* __restrict__ xbf, const u16* __restrict__ wcomb,
                  const float* __restrict__ bias, u16* __restrict__ hall) {
    const int jblk = blockIdx.x;   // 0..31 -> j slice of 16
    const int dir  = blockIdx.y;   // 0 fwd, 1 bwd
    const int t = threadIdx.x;
    const int w = t >> 6, l = t & 63;
    const int l16 = l & 15, lhi = l >> 4;
    const int kbase = w * 128;
    const bool isx = (w < 4);

    __shared__ float gred[8][64][69];   // 141 KiB; 69 stride -> ~2-way on reads

    // ---- B-fragments in registers (once): 4 gates x 4 k-tiles ----
    bf16x8 bfrag[4][4];
#pragma unroll
    for (int nf = 0; nf < 4; ++nf)
#pragma unroll
        for (int kt = 0; kt < 4; ++kt) {
            int gr = nf * NH + jblk * 16 + l16;          // gate nf, j-col l16
            int k = kbase + kt * 32 + lhi * 8;
            bfrag[nf][kt] = *reinterpret_cast<const bf16x8*>(
                wcomb + (size_t)(dir * NG + gr) * KC + k);
        }

    // ---- epilogue ownership: thread -> (bb = t>>3, jo = t&7 -> j0 = 2*jo) ----
    const int bb = t >> 3;
    const int jo = t & 7;
    const int j0 = jo * 2;
    float breg[4][2];
#pragma unroll
    for (int gi = 0; gi < 4; ++gi)
#pragma unroll
        for (int u = 0; u < 2; ++u)
            breg[gi][u] = bias[dir * NG + gi * NH + jblk * 16 + j0 + u];
    float c0 = 0.f, c1 = 0.f;   // cell state in registers

    u32* Hw = reinterpret_cast<u32*>(hall) + (size_t)dir * (HB / 2);
    const u64* Hq = reinterpret_cast<const u64*>(hall) + (size_t)dir * (HB / 4);

    for (int step = 0; step < NS; ++step) {
        const int s = dir ? (NS - 1 - step) : step;
        const int sprev = dir ? (s + 1) : (s - 1);

        f32x4 acc[4][4];
#pragma unroll
        for (int mf = 0; mf < 4; ++mf)
#pragma unroll
            for (int nf = 0; nf < 4; ++nf)
                acc[mf][nf] = (f32x4){0.f, 0.f, 0.f, 0.f};

        if (isx) {
            // x part: no cross-block dependency -> never waits
            const u16* Abase = xbf + (size_t)(s * NB) * NE + kbase;
#pragma unroll
            for (int kt = 0; kt < 4; ++kt) {
                int k = kt * 32 + lhi * 8;
#pragma unroll
                for (int mf = 0; mf < 4; ++mf) {
                    bf16x8 a = *reinterpret_cast<const bf16x8*>(Abase + (size_t)(mf * 16 + l16) * NE + k);
#pragma unroll
                    for (int nf = 0; nf < 4; ++nf)
                        acc[mf][nf] = __builtin_amdgcn_mfma_f32_16x16x32_bf16(a, bfrag[nf][kt], acc[mf][nf], 0, 0, 0);
                }
            }
        } else if (step > 0) {
            const int kloc = kbase - 512;
            // ---- load all 16 fragments once; validate; narrow retries ----
            u64 qa[4][4], qb[4][4];
            u32 okm = 0;
#pragma unroll
            for (int kt = 0; kt < 4; ++kt) {
                int j = kloc + kt * 32 + lhi * 8;
#pragma unroll
                for (int mf = 0; mf < 4; ++mf) {
                    const u64* P = Hq + (size_t)(sprev * NB + mf * 16 + l16) * 128 + (j >> 2);
                    u64 v0 = __hip_atomic_load(P,     __ATOMIC_RELAXED, __HIP_MEMORY_SCOPE_AGENT);
                    u64 v1 = __hip_atomic_load(P + 1, __ATOMIC_RELAXED, __HIP_MEMORY_SCOPE_AGENT);
                    qa[kt][mf] = v0; qb[kt][mf] = v1;
                    bool bad = ((u32)v0 == SENT32) | ((u32)(v0 >> 32) == SENT32)
                             | ((u32)v1 == SENT32) | ((u32)(v1 >> 32) == SENT32);
                    okm |= (bad ? 0u : 1u) << (kt * 4 + mf);
                }
            }
            while (__ballot(okm != 0xFFFFu)) {
                __builtin_amdgcn_s_sleep(1);
#pragma unroll
                for (int kt = 0; kt < 4; ++kt) {
                    int j = kloc + kt * 32 + lhi * 8;
#pragma unroll
                    for (int mf = 0; mf < 4; ++mf) {
                        u32 bit = 1u << (kt * 4 + mf);
                        if (!(okm & bit)) {
                            const u64* P = Hq + (size_t)(sprev * NB + mf * 16 + l16) * 128 + (j >> 2);
                            u64 v0 = __hip_atomic_load(P,     __ATOMIC_RELAXED, __HIP_MEMORY_SCOPE_AGENT);
                            u64 v1 = __hip_atomic_load(P + 1, __ATOMIC_RELAXED, __HIP_MEMORY_SCOPE_AGENT);
                            qa[kt][mf] = v0; qb[kt][mf] = v1;
                            bool bad = ((u32)v0 == SENT32) | ((u32)(v0 >> 32) == SENT32)
                                     | ((u32)v1 == SENT32) | ((u32)(v1 >> 32) == SENT32);
                            if (!bad) okm |= bit;
                        }
                    }
                }
            }
            __builtin_amdgcn_sched_barrier(0);
#pragma unroll
            for (int kt = 0; kt < 4; ++kt) {
#pragma unroll
                for (int mf = 0; mf < 4; ++mf) {
                    union { u64 q[2]; bf16x8 v; } cv;
                    cv.q[0] = qa[kt][mf]; cv.q[1] = qb[kt][mf];
#pragma unroll
                    for (int nf = 0; nf < 4; ++nf)
                        acc[mf][nf] = __builtin_amdgcn_mfma_f32_16x16x32_bf16(cv.v, bfrag[nf][kt], acc[mf][nf], 0, 0, 0);
                }
            }
        }

        // ---- dump partials ----
#pragma unroll
        for (int mf = 0; mf < 4; ++mf)
#pragma unroll
            for (int nf = 0; nf < 4; ++nf)
#pragma unroll
                for (int r = 0; r < 4; ++r)
                    gred[w][mf * 16 + lhi * 4 + r][nf * 16 + l16] = acc[mf][nf][r];
        __syncthreads();

        // ---- reduce 8 K-partials + cell update (c in regs), 2 cells/thread ----
        float g[2][4];
#pragma unroll
        for (int u = 0; u < 2; ++u)
#pragma unroll
            for (int gi = 0; gi < 4; ++gi) {
                int n = gi * 16 + j0 + u;
                float sum = gred[0][bb][n];
#pragma unroll
                for (int kw = 1; kw < 8; ++kw) sum += gred[kw][bb][n];
                g[u][gi] = sum + breg[gi][u];
            }
        float cn0 = sig_(g[0][1]) * c0 + sig_(g[0][0]) * tanh_(g[0][2]);
        float cn1 = sig_(g[1][1]) * c1 + sig_(g[1][0]) * tanh_(g[1][2]);
        c0 = cn0; c1 = cn1;
        u32 hw = (u32)f2bf(sig_(g[0][3]) * tanh_(cn0))
               | ((u32)f2bf(sig_(g[1][3]) * tanh_(cn1)) << 16);
        // fire-and-forget publish: h[s][bb][jblk*16 + j0..j0+1]
        __hip_atomic_store(Hw + (size_t)(s * NB + bb) * 256 + jblk * 8 + jo, hw,
                           __ATOMIC_RELAXED, __HIP_MEMORY_SCOPE_AGENT);
        __syncthreads();   // gred reuse protection; slack between publish & poll
    }
}

// ---------- emissions: one block per s; rows b=0..63 ----------
__global__ void emis_kernel(const u16* __restrict__ hall, const u16* __restrict__ woutbf,
                            const float* __restrict__ bout, float* __restrict__ emis) {
    const int blk = blockIdx.x;                   // = s, 512 blocks
    const int t = threadIdx.x;
    const int w = t >> 6, l = t & 63;
    const int l16 = l & 15, lhi = l >> 4;

    const u16* arow0 = hall + (size_t)(blk * 64 + w * 16 + l16) * NH;
    const u16* arow1 = arow0 + HB;
    const u16* br0 = woutbf + (size_t)(0 * 16 + l16) * KC;
    const u16* br1 = woutbf + (size_t)(1 * 16 + l16) * KC;
    const u16* br2 = woutbf + (size_t)(2 * 16 + l16) * KC;
    const u16* br3 = woutbf + (size_t)(3 * 16 + l16) * KC;

    f32x4 a0 = {0.f,0.f,0.f,0.f}, a1 = {0.f,0.f,0.f,0.f}, a2 = {0.f,0.f,0.f,0.f}, a3 = {0.f,0.f,0.f,0.f};
#pragma unroll
    for (int kt = 0; kt < 16; ++kt) {             // h_f part
        int k = kt * 32 + lhi * 8;
        bf16x8 a = *reinterpret_cast<const bf16x8*>(arow0 + k);
        a0 = __builtin_amdgcn_mfma_f32_16x16x32_bf16(a, *reinterpret_cast<const bf16x8*>(br0 + k), a0, 0, 0, 0);
        a1 = __builtin_amdgcn_mfma_f32_16x16x32_bf16(a, *reinterpret_cast<const bf16x8*>(br1 + k), a1, 0, 0, 0);
        a2 = __builtin_amdgcn_mfma_f32_16x16x32_bf16(a, *reinterpret_cast<const bf16x8*>(br2 + k), a2, 0, 0, 0);
        a3 = __builtin_amdgcn_mfma_f32_16x16x32_bf16(a, *reinterpret_cast<const bf16x8*>(br3 + k), a3, 0, 0, 0);
    }
#pragma unroll
    for (int kt = 0; kt < 16; ++kt) {             // h_b part
        int k = kt * 32 + lhi * 8;
        bf16x8 a = *reinterpret_cast<const bf16x8*>(arow1 + k);
        a0 = __builtin_amdgcn_mfma_f32_16x16x32_bf16(a, *reinterpret_cast<const bf16x8*>(br0 + NH + k), a0, 0, 0, 0);
        a1 = __builtin_amdgcn_mfma_f32_16x16x32_bf16(a, *reinterpret_cast<const bf16x8*>(br1 + NH + k), a1, 0, 0, 0);
        a2 = __builtin_amdgcn_mfma_f32_16x16x32_bf16(a, *reinterpret_cast<const bf16x8*>(br2 + NH + k), a2, 0, 0, 0);
        a3 = __builtin_amdgcn_mfma_f32_16x16x32_bf16(a, *reinterpret_cast<const bf16x8*>(br3 + NH + k), a3, 0, 0, 0);
    }
#pragma unroll
    for (int r = 0; r < 4; ++r) {
        int gm = blk * 64 + w * 16 + lhi * 4 + r;
        emis[(size_t)gm * NT + 0 * 16 + l16] = a0[r] + bout[0 * 16 + l16];
        emis[(size_t)gm * NT + 1 * 16 + l16] = a1[r] + bout[1 * 16 + l16];
        emis[(size_t)gm * NT + 2 * 16 + l16] = a2[r] + bout[2 * 16 + l16];
        emis[(size_t)gm * NT + 3 * 16 + l16] = a3[r] + bout[3 * 16 + l16];
    }
}

// ---------- gold score per batch ----------
__global__ void gold_kernel(const float* __restrict__ emis, const int* __restrict__ tags,
                            const float* __restrict__ trans, float* __restrict__ gold) {
    int b = blockIdx.x, t = threadIdx.x;
    float acc = 0.f;
    for (int s = t; s < NS; s += 256) {
        int tag = tags[b * NS + s];
        int prev = (s == 0) ? 0 : tags[b * NS + s - 1];
        acc += emis[(size_t)(s * NB + b) * NT + tag] + trans[tag * NT + prev];
    }
    acc += __shfl_xor(acc, 1);  acc += __shfl_xor(acc, 2);  acc += __shfl_xor(acc, 4);
    acc += __shfl_xor(acc, 8);  acc += __shfl_xor(acc, 16); acc += __shfl_xor(acc, 32);
    __shared__ float red[4];
    if ((t & 63) == 0) red[t >> 6] = acc;
    __syncthreads();
    if (t == 0) gold[b] = red[0] + red[1] + red[2] + red[3];
}

// ---------- CRF forward: 1 wave/block, transitions column in regs, no LDS ----------
__global__ void crf_kernel(const float* __restrict__ emis, const float* __restrict__ trans,
                           float* __restrict__ fwd) {
    int b = blockIdx.x, l = threadIdx.x;   // 64 threads; lane l = "next" tag
    float Tc[64];
#pragma unroll
    for (int p = 0; p < 64; ++p)
        Tc[p] = trans[l * NT + p];         // T[prev=p][next=l]
    float a = (l == 0) ? 0.f : NEGV;       // alpha in a register per lane

    for (int s = 0; s < NS; ++s) {
        float emit = emis[(size_t)(s * NB + b) * NT + l];
        float M = -3.0e38f;
#pragma unroll
        for (int p = 0; p < 64; ++p)
            M = fmaxf(M, __shfl(a, p) + Tc[p]);
        float S = 0.f;
#pragma unroll
        for (int p = 0; p < 64; ++p)
            S += __builtin_amdgcn_exp2f((__shfl(a, p) + Tc[p] - M) * 1.44269504f);
        a = M + __builtin_amdgcn_logf(S) * 0.69314718f + emit;
    }
    float M = a;
#pragma unroll
    for (int d = 1; d < 64; d <<= 1) M = fmaxf(M, __shfl_xor(M, d));
    float e = __builtin_amdgcn_exp2f((a - M) * 1.44269504f);
#pragma unroll
    for (int d = 1; d < 64; d <<= 1) e += __shfl_xor(e, d);
    if (l == 0) fwd[b] = M + __builtin_amdgcn_logf(e) * 0.69314718f;
}

// ---------- final: mean(fwd - gold) ----------
__global__ void final_kernel(const float* __restrict__ fwd, const float* __restrict__ gold,
                             float* __restrict__ out) {
    int t = threadIdx.x;   // 64
    float v = fwd[t] - gold[t];
    for (int d = 1; d < 64; d <<= 1) v += __shfl_xor(v, d);
    if (t == 0) out[0] = v * (1.0f / 64.0f);
}

extern "C" void kernel_launch(void* const* d_in, const int* in_sizes, int n_in,
                              void* d_out, int out_size, void* d_ws, size_t ws_size,
                              hipStream_t stream) {
    (void)in_sizes; (void)n_in; (void)out_size; (void)ws_size;
    const int* sents = (const int*)d_in[0];
    const int* tags  = (const int*)d_in[1];
    const float* emb  = (const float*)d_in[3];
    const float* wihf = (const float*)d_in[4];
    const float* whhf = (const float*)d_in[5];
    const float* bihf = (const float*)d_in[6];
    const float* bhhf = (const float*)d_in[7];
    const float* wihb = (const float*)d_in[8];
    const float* whhb = (const float*)d_in[9];
    const float* bihb = (const float*)d_in[10];
    const float* bhhb = (const float*)d_in[11];
    const float* wout = (const float*)d_in[12];
    const float* bout = (const float*)d_in[13];
    const float* trans = (const float*)d_in[14];

    char* ws = (char*)d_ws;
    u16*   WCOMB  = (u16*)(ws + 0);              //  8 MiB  [2][2048][1024] bf16
    u16*   WOUTBF = (u16*)(ws + 8388608);        //  128 KiB [64][1024] bf16
    float* BIAS   = (float*)(ws + 8519680);      //  16 KiB  [2][2048] f32
    u16*   XBF    = (u16*)(ws + 8536064);        //  32 MiB  [32768][512] bf16
    u16*   HALL   = (u16*)(ws + 42090496);       //  64 MiB  [2][512][64][512] bf16
    float* EMIS   = (float*)(ws + 109199360);    //  8 MiB   [512*64][64] f32
    float* FWD    = (float*)(ws + 117587968);    //  [64] f32
    float* GOLD   = (float*)(ws + 117588224);    //  [64] f32

    prep_wcomb<<<4096, 256, 0, stream>>>(wihf, whhf, wihb, whhb, WCOMB);
    prep_misc<<<272, 256, 0, stream>>>(wout, bihf, bhhf, bihb, bhhb, WOUTBF, BIAS);
    prep_hfill<<<16384, 256, 0, stream>>>((uint4*)HALL);
    prep_embed<<<16384, 256, 0, stream>>>(emb, sents, XBF);

    lstm_persist<<<dim3(32, 2), 512, 0, stream>>>(XBF, WCOMB, BIAS, HALL);

    emis_kernel<<<512, 256, 0, stream>>>(HALL, WOUTBF, bout, EMIS);
    gold_kernel<<<64, 256, 0, stream>>>(EMIS, tags, trans, GOLD);
    crf_kernel<<<64, 64, 0, stream>>>(EMIS, trans, FWD);
    final_kernel<<<1, 64, 0, stream>>>(FWD, GOLD, (float*)d_out);
}

// Round 12
// 3624.752 us; speedup vs baseline: 1.6575x; 1.2410x over previous
//
#include <hip/hip_runtime.h>

#define NB 64      // batch
#define NS 512     // seq len
#define NE 512     // emb dim
#define NH 512     // per-dir hidden
#define NG 2048    // 4*NH
#define NT 64      // tags
#define KC 1024    // combined K = NE + NH
#define HB 16777216   // u16 elements per direction in HALL
#define SENT32 0x7FC07FC0u  // bf16 NaN|NaN — unreachable for h = sig*tanh
#define NEGV (-10000.0f)

typedef __attribute__((ext_vector_type(8))) short bf16x8;
typedef __attribute__((ext_vector_type(4))) float f32x4;
typedef unsigned short u16;
typedef unsigned int u32;
typedef unsigned long long u64;

__device__ __forceinline__ u16 f2bf(float x) {
    unsigned u = __builtin_bit_cast(unsigned, x);
    u += 0x7fffu + ((u >> 16) & 1u);
    return (u16)(u >> 16);
}
__device__ __forceinline__ float sig_(float x) {
    return __builtin_amdgcn_rcpf(1.0f + __builtin_amdgcn_exp2f(-1.44269504f * x));
}
__device__ __forceinline__ float tanh_(float x) {
    return 2.0f * __builtin_amdgcn_rcpf(1.0f + __builtin_amdgcn_exp2f(-2.88539009f * x)) - 1.0f;
}

// ---------- prep: combined [W_ih | W_hh] -> bf16, [2][2048][1024] ----------
__global__ void prep_wcomb(const float* __restrict__ wihf, const float* __restrict__ whhf,
                           const float* __restrict__ wihb, const float* __restrict__ whhb,
                           u16* __restrict__ wcomb) {
    int idx = blockIdx.x * 256 + threadIdx.x;   // 1,048,576 threads, 4 elems each
    int base = idx * 4;
    int d = base >> 21;
    int rem = base & ((1 << 21) - 1);
    int n = rem >> 10;
    int k = rem & 1023;
    const float* wih = d ? wihb : wihf;
    const float* whh = d ? whhb : whhf;
    const float* src = (k < NE) ? (wih + n * NE + k) : (whh + n * NH + (k - NE));
    float4 v = *reinterpret_cast<const float4*>(src);
    ushort4 o;
    o.x = f2bf(v.x); o.y = f2bf(v.y); o.z = f2bf(v.z); o.w = f2bf(v.w);
    *reinterpret_cast<ushort4*>(wcomb + base) = o;
}

// ---------- prep: w_out->bf16, bias = b_ih+b_hh ----------
__global__ void prep_misc(const float* __restrict__ wout,
                          const float* __restrict__ bihf, const float* __restrict__ bhhf,
                          const float* __restrict__ bihb, const float* __restrict__ bhhb,
                          u16* __restrict__ woutbf, float* __restrict__ bias) {
    int idx = blockIdx.x * 256 + threadIdx.x;   // 272 blocks = 69,632 threads
    if (idx < 65536) { woutbf[idx] = f2bf(wout[idx]); return; }
    idx -= 65536;
    if (idx < 4096) {
        int d = idx >> 11, g = idx & 2047;
        bias[idx] = d ? (bihb[g] + bhhb[g]) : (bihf[g] + bhhf[g]);
    }
}

// ---------- prep: sentinel-fill HALL (64 MiB) ----------
__global__ void prep_hfill(uint4* __restrict__ h) {
    int idx = blockIdx.x * 256 + threadIdx.x;   // 16384 blocks
    uint4 v = {SENT32, SENT32, SENT32, SENT32};
    h[idx] = v;
}

// ---------- prep: embedding gather -> x_bf[(s*64+b)][512] bf16 ----------
__global__ void prep_embed(const float* __restrict__ emb, const int* __restrict__ sents,
                           u16* __restrict__ xbf) {
    int idx = blockIdx.x * 256 + threadIdx.x;   // 4,194,304 threads, 4 elems each
    int m = idx >> 7;
    int e = (idx & 127) << 2;
    int s = m >> 6, b = m & 63;
    int tok = sents[b * NS + s];
    float4 v = *reinterpret_cast<const float4*>(emb + (size_t)tok * NE + e);
    ushort4 o;
    o.x = f2bf(v.x); o.y = f2bf(v.y); o.z = f2bf(v.z); o.w = f2bf(v.w);
    *reinterpret_cast<ushort4*>(xbf + (size_t)m * NE + e) = o;
}

// ---------- persistent bi-LSTM: 2D partition (batch-half x j-slice-32) ----------
// grid ((bh 2) x (jblk 16) = 32, dir 2), 512 thr, 8 waves.
// Block owns batch rows [32bh,32bh+32) x j-cols [32jblk,32jblk+32).
// Consumer needs h[s-1][its rows][all j] <- produced by the 16 blocks of its
// own (dir, bh) sync domain: FAN-IN 16 (was 32). r7 protocol otherwise:
// sentinel-in-data, narrow per-fragment retry, poll-at-top (full iteration
// of slack after publish), fire-and-forget relaxed agent publish.
__global__ __launch_bounds__(512, 1)
void lstm_persist(const u16* __restrict__ xbf, const u16* __restrict__ wcomb,
                  const float* __restrict__ bias, u16* __restrict__ hall) {
    const int bh   = blockIdx.x >> 4;   // 0..1 batch half
    const int jblk = blockIdx.x & 15;   // 0..15 -> j slice of 32
    const int dir  = blockIdx.y;        // 0 fwd, 1 bwd
    const int t = threadIdx.x;
    const int w = t >> 6, l = t & 63;
    const int l16 = l & 15, lhi = l >> 4;
    const int kbase = w * 128;
    const bool isx = (w < 4);

    __shared__ float gred[8][32][134];   // 134 KiB partial-gate buffer

    // ---- B-fragments in registers (once): 8 nf (4 gates x 2 cols16) x 4 kt ----
    bf16x8 bfrag[8][4];
#pragma unroll
    for (int nf = 0; nf < 8; ++nf)
#pragma unroll
        for (int kt = 0; kt < 4; ++kt) {
            int gr = (nf >> 1) * NH + jblk * 32 + (nf & 1) * 16 + l16;
            int k = kbase + kt * 32 + lhi * 8;
            bfrag[nf][kt] = *reinterpret_cast<const bf16x8*>(
                wcomb + (size_t)(dir * NG + gr) * KC + k);
        }

    // ---- epilogue ownership: thread -> (row = t>>4 of 32, jo = t&15 -> 2 j) ----
    const int row = t >> 4;
    const int jo  = t & 15;
    const int j0  = jo * 2;
    float breg[4][2];
#pragma unroll
    for (int gi = 0; gi < 4; ++gi)
#pragma unroll
        for (int u = 0; u < 2; ++u)
            breg[gi][u] = bias[dir * NG + gi * NH + jblk * 32 + j0 + u];
    float c0 = 0.f, c1 = 0.f;   // cell state in registers

    u32* Hw = reinterpret_cast<u32*>(hall) + (size_t)dir * (HB / 2);
    const u64* Hq = reinterpret_cast<const u64*>(hall) + (size_t)dir * (HB / 4);

    for (int step = 0; step < NS; ++step) {
        const int s = dir ? (NS - 1 - step) : step;
        const int sprev = dir ? (s + 1) : (s - 1);

        f32x4 acc[2][8];
#pragma unroll
        for (int mf = 0; mf < 2; ++mf)
#pragma unroll
            for (int nf = 0; nf < 8; ++nf)
                acc[mf][nf] = (f32x4){0.f, 0.f, 0.f, 0.f};

        if (isx) {
            // x part: no cross-block dependency -> never waits
            const u16* Abase = xbf + (size_t)(s * NB + bh * 32) * NE + kbase;
#pragma unroll
            for (int kt = 0; kt < 4; ++kt) {
                int k = kt * 32 + lhi * 8;
#pragma unroll
                for (int mf = 0; mf < 2; ++mf) {
                    bf16x8 a = *reinterpret_cast<const bf16x8*>(Abase + (size_t)(mf * 16 + l16) * NE + k);
#pragma unroll
                    for (int nf = 0; nf < 8; ++nf)
                        acc[mf][nf] = __builtin_amdgcn_mfma_f32_16x16x32_bf16(a, bfrag[nf][kt], acc[mf][nf], 0, 0, 0);
                }
            }
        } else if (step > 0) {
            const int kloc = kbase - 512;
            // ---- load all 8 fragments once; validate; narrow retries ----
            u64 qa[4][2], qb[4][2];
            u32 okm = 0;   // bit = kt*2 + mf, full = 0xFF
#pragma unroll
            for (int kt = 0; kt < 4; ++kt) {
                int j = kloc + kt * 32 + lhi * 8;
#pragma unroll
                for (int mf = 0; mf < 2; ++mf) {
                    const u64* P = Hq + (size_t)(sprev * NB + bh * 32 + mf * 16 + l16) * 128 + (j >> 2);
                    u64 v0 = __hip_atomic_load(P,     __ATOMIC_RELAXED, __HIP_MEMORY_SCOPE_AGENT);
                    u64 v1 = __hip_atomic_load(P + 1, __ATOMIC_RELAXED, __HIP_MEMORY_SCOPE_AGENT);
                    qa[kt][mf] = v0; qb[kt][mf] = v1;
                    bool bad = ((u32)v0 == SENT32) | ((u32)(v0 >> 32) == SENT32)
                             | ((u32)v1 == SENT32) | ((u32)(v1 >> 32) == SENT32);
                    okm |= (bad ? 0u : 1u) << (kt * 2 + mf);
                }
            }
            while (__ballot(okm != 0xFFu)) {
                __builtin_amdgcn_s_sleep(1);
#pragma unroll
                for (int kt = 0; kt < 4; ++kt) {
                    int j = kloc + kt * 32 + lhi * 8;
#pragma unroll
                    for (int mf = 0; mf < 2; ++mf) {
                        u32 bit = 1u << (kt * 2 + mf);
                        if (!(okm & bit)) {
                            const u64* P = Hq + (size_t)(sprev * NB + bh * 32 + mf * 16 + l16) * 128 + (j >> 2);
                            u64 v0 = __hip_atomic_load(P,     __ATOMIC_RELAXED, __HIP_MEMORY_SCOPE_AGENT);
                            u64 v1 = __hip_atomic_load(P + 1, __ATOMIC_RELAXED, __HIP_MEMORY_SCOPE_AGENT);
                            qa[kt][mf] = v0; qb[kt][mf] = v1;
                            bool bad = ((u32)v0 == SENT32) | ((u32)(v0 >> 32) == SENT32)
                                     | ((u32)v1 == SENT32) | ((u32)(v1 >> 32) == SENT32);
                            if (!bad) okm |= bit;
                        }
                    }
                }
            }
            __builtin_amdgcn_sched_barrier(0);
#pragma unroll
            for (int kt = 0; kt < 4; ++kt) {
#pragma unroll
                for (int mf = 0; mf < 2; ++mf) {
                    union { u64 q[2]; bf16x8 v; } cv;
                    cv.q[0] = qa[kt][mf]; cv.q[1] = qb[kt][mf];
#pragma unroll
                    for (int nf = 0; nf < 8; ++nf)
                        acc[mf][nf] = __builtin_amdgcn_mfma_f32_16x16x32_bf16(cv.v, bfrag[nf][kt], acc[mf][nf], 0, 0, 0);
                }
            }
        }

        // ---- dump partials ----
#pragma unroll
        for (int mf = 0; mf < 2; ++mf)
#pragma unroll
            for (int nf = 0; nf < 8; ++nf)
#pragma unroll
                for (int r = 0; r < 4; ++r)
                    gred[w][mf * 16 + lhi * 4 + r][nf * 16 + l16] = acc[mf][nf][r];
        __syncthreads();

        // ---- reduce 8 K-partials + cell update (c in regs), 2 cells/thread ----
        float g[2][4];
#pragma unroll
        for (int u = 0; u < 2; ++u)
#pragma unroll
            for (int gi = 0; gi < 4; ++gi) {
                int n = gi * 32 + j0 + u;
                float sum = gred[0][row][n];
#pragma unroll
                for (int kw = 1; kw < 8; ++kw) sum += gred[kw][row][n];
                g[u][gi] = sum + breg[gi][u];
            }
        float cn0 = sig_(g[0][1]) * c0 + sig_(g[0][0]) * tanh_(g[0][2]);
        float cn1 = sig_(g[1][1]) * c1 + sig_(g[1][0]) * tanh_(g[1][2]);
        c0 = cn0; c1 = cn1;
        u32 hw = (u32)f2bf(sig_(g[0][3]) * tanh_(cn0))
               | ((u32)f2bf(sig_(g[1][3]) * tanh_(cn1)) << 16);
        // fire-and-forget publish: h[s][bh*32+row][jblk*32 + j0..j0+1]
        __hip_atomic_store(Hw + (size_t)(s * NB + bh * 32 + row) * 256 + jblk * 16 + jo, hw,
                           __ATOMIC_RELAXED, __HIP_MEMORY_SCOPE_AGENT);
        __syncthreads();   // gred reuse protection; slack between publish & poll
    }
}

// ---------- emissions: one block per s; rows b=0..63 ----------
__global__ void emis_kernel(const u16* __restrict__ hall, const u16* __restrict__ woutbf,
                            const float* __restrict__ bout, float* __restrict__ emis) {
    const int blk = blockIdx.x;                   // = s, 512 blocks
    const int t = threadIdx.x;
    const int w = t >> 6, l = t & 63;
    const int l16 = l & 15, lhi = l >> 4;

    const u16* arow0 = hall + (size_t)(blk * 64 + w * 16 + l16) * NH;
    const u16* arow1 = arow0 + HB;
    const u16* br0 = woutbf + (size_t)(0 * 16 + l16) * KC;
    const u16* br1 = woutbf + (size_t)(1 * 16 + l16) * KC;
    const u16* br2 = woutbf + (size_t)(2 * 16 + l16) * KC;
    const u16* br3 = woutbf + (size_t)(3 * 16 + l16) * KC;

    f32x4 a0 = {0.f,0.f,0.f,0.f}, a1 = {0.f,0.f,0.f,0.f}, a2 = {0.f,0.f,0.f,0.f}, a3 = {0.f,0.f,0.f,0.f};
#pragma unroll
    for (int kt = 0; kt < 16; ++kt) {             // h_f part
        int k = kt * 32 + lhi * 8;
        bf16x8 a = *reinterpret_cast<const bf16x8*>(arow0 + k);
        a0 = __builtin_amdgcn_mfma_f32_16x16x32_bf16(a, *reinterpret_cast<const bf16x8*>(br0 + k), a0, 0, 0, 0);
        a1 = __builtin_amdgcn_mfma_f32_16x16x32_bf16(a, *reinterpret_cast<const bf16x8*>(br1 + k), a1, 0, 0, 0);
        a2 = __builtin_amdgcn_mfma_f32_16x16x32_bf16(a, *reinterpret_cast<const bf16x8*>(br2 + k), a2, 0, 0, 0);
        a3 = __builtin_amdgcn_mfma_f32_16x16x32_bf16(a, *reinterpret_cast<const bf16x8*>(br3 + k), a3, 0, 0, 0);
    }
#pragma unroll
    for (int kt = 0; kt < 16; ++kt) {             // h_b part
        int k = kt * 32 + lhi * 8;
        bf16x8 a = *reinterpret_cast<const bf16x8*>(arow1 + k);
        a0 = __builtin_amdgcn_mfma_f32_16x16x32_bf16(a, *reinterpret_cast<const bf16x8*>(br0 + NH + k), a0, 0, 0, 0);
        a1 = __builtin_amdgcn_mfma_f32_16x16x32_bf16(a, *reinterpret_cast<const bf16x8*>(br1 + NH + k), a1, 0, 0, 0);
        a2 = __builtin_amdgcn_mfma_f32_16x16x32_bf16(a, *reinterpret_cast<const bf16x8*>(br2 + NH + k), a2, 0, 0, 0);
        a3 = __builtin_amdgcn_mfma_f32_16x16x32_bf16(a, *reinterpret_cast<const bf16x8*>(br3 + NH + k), a3, 0, 0, 0);
    }
#pragma unroll
    for (int r = 0; r < 4; ++r) {
        int gm = blk * 64 + w * 16 + lhi * 4 + r;
        emis[(size_t)gm * NT + 0 * 16 + l16] = a0[r] + bout[0 * 16 + l16];
        emis[(size_t)gm * NT + 1 * 16 + l16] = a1[r] + bout[1 * 16 + l16];
        emis[(size_t)gm * NT + 2 * 16 + l16] = a2[r] + bout[2 * 16 + l16];
        emis[(size_t)gm * NT + 3 * 16 + l16] = a3[r] + bout[3 * 16 + l16];
    }
}

// ---------- gold score per batch ----------
__global__ void gold_kernel(const float* __restrict__ emis, const int* __restrict__ tags,
                            const float* __restrict__ trans, float* __restrict__ gold) {
    int b = blockIdx.x, t = threadIdx.x;
    float acc = 0.f;
    for (int s = t; s < NS; s += 256) {
        int tag = tags[b * NS + s];
        int prev = (s == 0) ? 0 : tags[b * NS + s - 1];
        acc += emis[(size_t)(s * NB + b) * NT + tag] + trans[tag * NT + prev];
    }
    acc += __shfl_xor(acc, 1);  acc += __shfl_xor(acc, 2);  acc += __shfl_xor(acc, 4);
    acc += __shfl_xor(acc, 8);  acc += __shfl_xor(acc, 16); acc += __shfl_xor(acc, 32);
    __shared__ float red[4];
    if ((t & 63) == 0) red[t >> 6] = acc;
    __syncthreads();
    if (t == 0) gold[b] = red[0] + red[1] + red[2] + red[3];
}

// ---------- CRF forward: 1 wave/block, transitions column in regs, no LDS ----------
__global__ void crf_kernel(const float* __restrict__ emis, const float* __restrict__ trans,
                           float* __restrict__ fwd) {
    int b = blockIdx.x, l = threadIdx.x;   // 64 threads; lane l = "next" tag
    float Tc[64];
#pragma unroll
    for (int p = 0; p < 64; ++p)
        Tc[p] = trans[l * NT + p];         // T[prev=p][next=l]
    float a = (l == 0) ? 0.f : NEGV;       // alpha in a register per lane

    for (int s = 0; s < NS; ++s) {
        float emit = emis[(size_t)(s * NB + b) * NT + l];
        float M = -3.0e38f;
#pragma unroll
        for (int p = 0; p < 64; ++p)
            M = fmaxf(M, __shfl(a, p) + Tc[p]);
        float S = 0.f;
#pragma unroll
        for (int p = 0; p < 64; ++p)
            S += __builtin_amdgcn_exp2f((__shfl(a, p) + Tc[p] - M) * 1.44269504f);
        a = M + __builtin_amdgcn_logf(S) * 0.69314718f + emit;
    }
    float M = a;
#pragma unroll
    for (int d = 1; d < 64; d <<= 1) M = fmaxf(M, __shfl_xor(M, d));
    float e = __builtin_amdgcn_exp2f((a - M) * 1.44269504f);
#pragma unroll
    for (int d = 1; d < 64; d <<= 1) e += __shfl_xor(e, d);
    if (l == 0) fwd[b] = M + __builtin_amdgcn_logf(e) * 0.69314718f;
}

// ---------- final: mean(fwd - gold) ----------
__global__ void final_kernel(const float* __restrict__ fwd, const float* __restrict__ gold,
                             float* __restrict__ out) {
    int t = threadIdx.x;   // 64
    float v = fwd[t] - gold[t];
    for (int d = 1; d < 64; d <<= 1) v += __shfl_xor(v, d);
    if (t == 0) out[0] = v * (1.0f / 64.0f);
}

extern "C" void kernel_launch(void* const* d_in, const int* in_sizes, int n_in,
                              void* d_out, int out_size, void* d_ws, size_t ws_size,
                              hipStream_t stream) {
    (void)in_sizes; (void)n_in; (void)out_size; (void)ws_size;
    const int* sents = (const int*)d_in[0];
    const int* tags  = (const int*)d_in[1];
    const float* emb  = (const float*)d_in[3];
    const float* wihf = (const float*)d_in[4];
    const float* whhf = (const float*)d_in[5];
    const float* bihf = (const float*)d_in[6];
    const float* bhhf = (const float*)d_in[7];
    const float* wihb = (const float*)d_in[8];
    const float* whhb = (const float*)d_in[9];
    const float* bihb = (const float*)d_in[10];
    const float* bhhb = (const float*)d_in[11];
    const float* wout = (const float*)d_in[12];
    const float* bout = (const float*)d_in[13];
    const float* trans = (const float*)d_in[14];

    char* ws = (char*)d_ws;
    u16*   WCOMB  = (u16*)(ws + 0);              //  8 MiB  [2][2048][1024] bf16
    u16*   WOUTBF = (u16*)(ws + 8388608);        //  128 KiB [64][1024] bf16
    float* BIAS   = (float*)(ws + 8519680);      //  16 KiB  [2][2048] f32
    u16*   XBF    = (u16*)(ws + 8536064);        //  32 MiB  [32768][512] bf16
    u16*   HALL   = (u16*)(ws + 42090496);       //  64 MiB  [2][512][64][512] bf16
    float* EMIS   = (float*)(ws + 109199360);    //  8 MiB   [512*64][64] f32
    float* FWD    = (float*)(ws + 117587968);    //  [64] f32
    float* GOLD   = (float*)(ws + 117588224);    //  [64] f32

    prep_wcomb<<<4096, 256, 0, stream>>>(wihf, whhf, wihb, whhb, WCOMB);
    prep_misc<<<272, 256, 0, stream>>>(wout, bihf, bhhf, bihb, bhhb, WOUTBF, BIAS);
    prep_hfill<<<16384, 256, 0, stream>>>((uint4*)HALL);
    prep_embed<<<16384, 256, 0, stream>>>(emb, sents, XBF);

    lstm_persist<<<dim3(32, 2), 512, 0, stream>>>(XBF, WCOMB, BIAS, HALL);

    emis_kernel<<<512, 256, 0, stream>>>(HALL, WOUTBF, bout, EMIS);
    gold_kernel<<<64, 256, 0, stream>>>(EMIS, tags, trans, GOLD);
    crf_kernel<<<64, 64, 0, stream>>>(EMIS, trans, FWD);
    final_kernel<<<1, 64, 0, stream>>>(FWD, GOLD, (float*)d_out);
}